// Round 11
// baseline (4585.183 us; speedup 1.0000x reference)
//
#include <hip/hip_runtime.h>
#include <hip/hip_bf16.h>
#include <hip/hip_fp8.h>
#include <math.h>

// Encoder GRU, B=8192 T=256 H=512 — sync-free state-resident, v14.
// = v8 EXACTLY (per-wave flags, HW fp8 cvt, dbuf state, register ping-pong
// B, paired dwordx4 B loads, setprio) + NON-TEMPORAL B-stream loads
// (__builtin_nontemporal_load -> global_load_dwordx4 ... nt).
// Why: v8's step time IS the B-stream (768 KB/CU/step from L2 at ~70 GB/s/CU
// = 53% of per-XCD L2 BW); MFMA+epilogue hide under it. The stream has ZERO
// L1 reuse (each byte read once/step, 768KB >> 32KB L1) so every load pays
// L1 fill/evict overhead for nothing — the nt path streams past L1.
// v9-v13 post-mortems: deeper reg ring spills (128-reg/wave cap), LDS ring
// serializes, rotation loses locality, MX-scaled MFMA spills at this
// occupancy and is stream-capped anyway. Attack the stream itself.
// d_in: x(B,T), kmforenc(T), dense_kernel(1,H), dense_bias(H),
//       gru_kernel(H,3H), gru_recurrent(H,3H), gru_bias(2,3H)

constexpr int B_  = 8192;
constexpr int T_  = 256;
constexpr int H_  = 512;
constexpr int H3_ = 1536;
constexpr size_t BH = (size_t)B_ * H_;
constexpr int ROWS = 32;

typedef float f32x4 __attribute__((ext_vector_type(4)));
typedef long  lx2   __attribute__((ext_vector_type(2)));

__device__ __forceinline__ unsigned char f2e4m3(float f) {
    __hip_fp8_e4m3 v(f); return v.__x;
}
// swizzled byte offset into one fp8 state plane [32 rows][512 cols]
__device__ __forceinline__ int swz(int row, int col) {
    return (row * 512 + col) ^ ((row & 15) << 3);
}
__device__ __forceinline__ float fast_sigmoid(float v) {
    return __builtin_amdgcn_rcpf(1.f + __expf(-v));
}
__device__ __forceinline__ float fast_tanh(float v) {
    float a = fabsf(v);
    float e = __expf(-2.f * a);
    float t = (1.f - e) * __builtin_amdgcn_rcpf(1.f + e);
    return copysignf(t, v);
}

// wx[j] = sum_h dense_kernel[h]*gru_kernel[h,j]
// cc[j] = sum_h dense_bias[h]*gru_kernel[h,j] + gru_bias[0][j]
__global__ void prep_wx(const float* __restrict__ dk,
                        const float* __restrict__ db,
                        const float* __restrict__ K,
                        const float* __restrict__ gb,
                        float* __restrict__ wx,
                        float* __restrict__ cc) {
    int j = blockIdx.x * blockDim.x + threadIdx.x;
    if (j >= H3_) return;
    float a = 0.f, c = 0.f;
    for (int h = 0; h < H_; ++h) {
        float kv = K[(size_t)h * H3_ + j];
        a = fmaf(dk[h], kv, a);
        c = fmaf(db[h], kv, c);
    }
    wx[j] = a;
    cc[j] = c + gb[j];
}

// Pack R (H x 3H row-major) into per-(kc,w) fragment-PAIR blocks so one
// dwordx4 per lane fetches two MFMA B fragments:
//   pair block (kc,w,p): 128 ulongs; lane L holds ulongs [2L, 2L+1] =
//   frag f=2p and f=2p+1 lane-L data.
//   frag f: n = g*512 + w*32 + q*16 + (lane&15), k = kc*32 + 8*(lane>>4)+e,
//   with g=f>>1, q=f&1 (p==g, j==q).
__global__ void pack_Rf8(const float* __restrict__ R,
                         unsigned long long* __restrict__ Rp) {
    int idx  = blockIdx.x * 256 + threadIdx.x;    // < 98304
    int lane = idx & 63;
    int fi   = idx >> 6;                          // 0..1535
    int f    = fi % 6;
    int rest = fi / 6;                            // kc*16 + w
    int g    = f >> 1, q = f & 1;
    int w    = rest & 15;
    int n    = g * 512 + w * 32 + q * 16 + (lane & 15);
    int kb   = (rest >> 4) * 32 + 8 * (lane >> 4);
    unsigned long long v = 0;
    #pragma unroll
    for (int e = 0; e < 8; ++e)
        v |= (unsigned long long)f2e4m3(R[(size_t)(kb + e) * H3_ + n]) << (8 * e);
    Rp[(size_t)(rest * 3 + g) * 128 + 2 * lane + q] = v;
}

__global__ __launch_bounds__(1024, 4) void gru_f8(
    const float* __restrict__ x, const float* __restrict__ km,
    const unsigned long long* __restrict__ Rp,
    const float* __restrict__ wx, const float* __restrict__ cc,
    const float* __restrict__ b1,
    float* __restrict__ out0, float* __restrict__ out1)
{
    __shared__ __align__(16) unsigned char st[2][ROWS * 512]; // dbuf fp8 state
    __shared__ float rkm[T_];
    __shared__ int flags[16];                     // steps completed per wave

    const int tid  = threadIdx.x;
    const int lane = tid & 63;
    const int w    = tid >> 6;                    // wave 0..15 -> cols [w*32,+32)
    const int l15  = lane & 15;
    const int lh   = lane >> 4;                   // 0..3
    const int row0 = blockIdx.x * ROWS;
    const bool odd1 = (l15 & 1) != 0;
    const bool odd2 = (l15 & 2) != 0;
    volatile int* vflag = (volatile int*)flags;

    if (tid < T_) rkm[tid] = 1.f / km[tid];
    if (tid < 16) flags[tid] = 0;

    // per-thread gate constants (loop-invariant)
    const int jcq[2] = { w * 32 + l15, w * 32 + 16 + l15 };
    float wxz[2], wxr[2], wxh[2], czc[2], crc[2], cch[2], b1h[2];
    #pragma unroll
    for (int q = 0; q < 2; ++q) {
        int jc = jcq[q];
        wxz[q] = wx[jc];  wxr[q] = wx[512 + jc];  wxh[q] = wx[1024 + jc];
        czc[q] = cc[jc]        + b1[jc];
        crc[q] = cc[512 + jc]  + b1[512 + jc];
        cch[q] = cc[1024 + jc];
        b1h[q] = b1[1024 + jc];
    }

    float hprev[2][2][4];                         // [q][mi][rr] fp32 carry
    #pragma unroll
    for (int q = 0; q < 2; ++q)
        #pragma unroll
        for (int mi = 0; mi < 2; ++mi)
            #pragma unroll
            for (int rr = 0; rr < 4; ++rr) hprev[q][mi][rr] = 0.f;

    // B stream: pair block stride 128 ulongs, kc stride 16*3*128 = 6144
    const unsigned long long* wb = Rp + (size_t)w * 384 + 2 * lane;

    __syncthreads();   // rkm + flags init visible (only barrier in kernel)

    // depth-1 ping-pong: B0 enters each step holding kc=0 (loaded at the
    // previous step's kc=14 phase B wrap, flying through the epilogue).
    // ALL B loads are non-temporal: stream past L1 (zero L1 reuse), L2-hit.
    lx2 B0[3], B1[3];
    #pragma unroll
    for (int p = 0; p < 3; ++p)
        B0[p] = __builtin_nontemporal_load((const lx2*)(wb + p * 128)); // kc=0

    #pragma unroll 1
    for (int t = 0; t < T_; ++t) {
        const char* rd = (const char*)st[t & 1];           // old state
        char*       wr = (char*)st[(t & 1) ^ 1];           // new state

        f32x4 acc[6][2];
        #pragma unroll
        for (int f = 0; f < 6; ++f) {
            acc[f][0] = (f32x4){0.f, 0.f, 0.f, 0.f};
            acc[f][1] = (f32x4){0.f, 0.f, 0.f, 0.f};
        }

        if (t > 0) {
            #pragma unroll 1
            for (int kc = 0; kc < 16; kc += 2) {
                // phase A: prefetch kc+1 -> B1, compute kc with B0
                #pragma unroll
                for (int p = 0; p < 3; ++p)
                    B1[p] = __builtin_nontemporal_load(
                        (const lx2*)(wb + (size_t)(kc + 1) * 6144 + p * 128));
                // wait for producer wave kc's step t-1 epilogue
                while (vflag[kc] < t) __builtin_amdgcn_s_sleep(1);
                asm volatile("" ::: "memory");
                long A0 = *(const long*)(rd + swz(l15,      kc * 32 + lh * 8));
                long A1 = *(const long*)(rd + swz(l15 + 16, kc * 32 + lh * 8));
                __builtin_amdgcn_s_setprio(1);
                #pragma unroll
                for (int p = 0; p < 3; ++p) {
                    #pragma unroll
                    for (int j = 0; j < 2; ++j) {
                        const int f = 2 * p + j;
                        acc[f][0] = __builtin_amdgcn_mfma_f32_16x16x32_fp8_fp8(
                            A0, B0[p][j], acc[f][0], 0, 0, 0);
                        acc[f][1] = __builtin_amdgcn_mfma_f32_16x16x32_fp8_fp8(
                            A1, B0[p][j], acc[f][1], 0, 0, 0);
                    }
                }
                __builtin_amdgcn_s_setprio(0);
                // phase B: prefetch (kc+2)&15 -> B0 (wraps to next step's
                // kc=0 at kc==14 — flies through the epilogue).
                #pragma unroll
                for (int p = 0; p < 3; ++p)
                    B0[p] = __builtin_nontemporal_load(
                        (const lx2*)(wb + (size_t)((kc + 2) & 15) * 6144 + p * 128));
                while (vflag[kc + 1] < t) __builtin_amdgcn_s_sleep(1);
                asm volatile("" ::: "memory");
                A0 = *(const long*)(rd + swz(l15,      (kc + 1) * 32 + lh * 8));
                A1 = *(const long*)(rd + swz(l15 + 16, (kc + 1) * 32 + lh * 8));
                __builtin_amdgcn_s_setprio(1);
                #pragma unroll
                for (int p = 0; p < 3; ++p) {
                    #pragma unroll
                    for (int j = 0; j < 2; ++j) {
                        const int f = 2 * p + j;
                        acc[f][0] = __builtin_amdgcn_mfma_f32_16x16x32_fp8_fp8(
                            A0, B1[p][j], acc[f][0], 0, 0, 0);
                        acc[f][1] = __builtin_amdgcn_mfma_f32_16x16x32_fp8_fp8(
                            A1, B1[p][j], acc[f][1], 0, 0, 0);
                    }
                }
                __builtin_amdgcn_s_setprio(0);
            }
        }

        // gates + state update; reads old plane (rd), writes new plane (wr).
        const float rk = rkm[t];
        #pragma unroll
        for (int mi = 0; mi < 2; ++mi) {
            #pragma unroll
            for (int rr = 0; rr < 4; ++rr) {
                const int brow = mi * 16 + lh * 4 + rr;
                const float cb = ((t == 0)
                    ? x[(size_t)(row0 + brow) * T_]
                    : __builtin_amdgcn_cvt_f32_fp8(
                          (int)((const unsigned char*)rd)[swz(brow, t)], 0)) * rk;
                #pragma unroll
                for (int q = 0; q < 2; ++q) {
                    float z   = fast_sigmoid(fmaf(cb, wxz[q], czc[q])
                                             + acc[q][mi][rr]);
                    float r   = fast_sigmoid(fmaf(cb, wxr[q], crc[q])
                                             + acc[2 + q][mi][rr]);
                    float mhh = acc[4 + q][mi][rr] + b1h[q];
                    float hh  = fast_tanh(fmaf(r, mhh, fmaf(cb, wxh[q], cch[q])));
                    float hn  = fmaf(z, hprev[q][mi][rr] - hh, hh);
                    hprev[q][mi][rr] = hn;
                    // pack 4 consecutive cols (across l15 quads) into one dword:
                    // DPP xor1 swap -> HW cvt_pk (ordered pair) -> xor2 merge.
                    float nb = __shfl_xor(hn, 1);
                    float lo = odd1 ? nb : hn;
                    float hi = odd1 ? hn : nb;
                    unsigned int w16 = (unsigned int)
                        __builtin_amdgcn_cvt_pk_fp8_f32(lo, hi, 0, false);
                    unsigned int v16 = (unsigned int)__shfl_xor((int)w16, 2);
                    unsigned int w32 = (odd2 ? v16 : w16)
                                     | ((odd2 ? w16 : v16) << 16);
                    if ((l15 & 3) == 0)
                        *(unsigned int*)(wr + swz(brow, w * 32 + q * 16 + l15)) = w32;
                }
            }
        }

        // publish: all this wave's LDS reads (phases + colb) and writes done,
        // then raise flag. Consumers spin on it; no block barrier.
        asm volatile("s_waitcnt lgkmcnt(0)" ::: "memory");
        if (lane == 0) vflag[w] = t + 1;
    }

    // final state from fp32 register carry -> both output halves
    #pragma unroll
    for (int q = 0; q < 2; ++q)
        #pragma unroll
        for (int mi = 0; mi < 2; ++mi)
            #pragma unroll
            for (int rr = 0; rr < 4; ++rr) {
                int brow = mi * 16 + lh * 4 + rr;
                size_t o = (size_t)(row0 + brow) * H_ + jcq[q];
                float v = hprev[q][mi][rr];
                out0[o] = v;
                out1[o] = v;
            }
}

extern "C" void kernel_launch(void* const* d_in, const int* in_sizes, int n_in,
                              void* d_out, int out_size, void* d_ws, size_t ws_size,
                              hipStream_t stream) {
    const float* x  = (const float*)d_in[0];
    const float* km = (const float*)d_in[1];
    const float* dk = (const float*)d_in[2];
    const float* db = (const float*)d_in[3];
    const float* K  = (const float*)d_in[4];
    const float* R  = (const float*)d_in[5];
    const float* gb = (const float*)d_in[6];

    float* out  = (float*)d_out;
    float* out1 = out + BH;

    float* wx = (float*)d_ws;                     // 1536 f
    float* cc = wx + H3_;                         // 1536 f
    unsigned long long* Rp = (unsigned long long*)(cc + H3_);   // 768 KB

    prep_wx<<<dim3((H3_ + 255) / 256), 256, 0, stream>>>(dk, db, K, gb, wx, cc);
    pack_Rf8<<<dim3(384), 256, 0, stream>>>(R, Rp);

    gru_f8<<<dim3(256), dim3(1024), 0, stream>>>(
        x, km, Rp, wx, cc, gb + H3_, out, out1);
}

// Round 12
// 3567.045 us; speedup vs baseline: 1.2854x; 1.2854x over previous
//
#include <hip/hip_runtime.h>
#include <hip/hip_bf16.h>
#include <hip/hip_fp8.h>
#include <math.h>

// Encoder GRU, B=8192 T=256 H=512 — sync-free state-resident, v15.
// = v8 (per-wave flags, HW fp8 cvt, dbuf state, register ping-pong B,
// paired dwordx4 B loads, setprio) + two surgical latency removals:
//  (1) PIPELINED FLAG CHECKS: prefetch flags[kc+2],flags[kc+3] into regs
//      during body kc; next body checks registers (2 cy) instead of a
//      volatile LDS round trip (~140 cy x32/step ≈ 1.9 us). Flags are
//      monotone -> stale>=t is a safe pass; stale<t falls back to the
//      original volatile spin. Correctness identical.
//  (2) BATCHED A-READS: both phases' ds_read_b64s issued together at body
//      top (post flag checks) so A(kc+1) latency hides under MFMA(kc).
// v14 post-mortem: nontemporal loads evicted Rp from L2 (FETCH 21MB->480MB,
// dur +60%) — nt is wrong for L2-resident streams. Reverted.
// d_in: x(B,T), kmforenc(T), dense_kernel(1,H), dense_bias(H),
//       gru_kernel(H,3H), gru_recurrent(H,3H), gru_bias(2,3H)

constexpr int B_  = 8192;
constexpr int T_  = 256;
constexpr int H_  = 512;
constexpr int H3_ = 1536;
constexpr size_t BH = (size_t)B_ * H_;
constexpr int ROWS = 32;

typedef float f32x4 __attribute__((ext_vector_type(4)));
typedef long  lx2   __attribute__((ext_vector_type(2)));

__device__ __forceinline__ unsigned char f2e4m3(float f) {
    __hip_fp8_e4m3 v(f); return v.__x;
}
// swizzled byte offset into one fp8 state plane [32 rows][512 cols]
__device__ __forceinline__ int swz(int row, int col) {
    return (row * 512 + col) ^ ((row & 15) << 3);
}
__device__ __forceinline__ float fast_sigmoid(float v) {
    return __builtin_amdgcn_rcpf(1.f + __expf(-v));
}
__device__ __forceinline__ float fast_tanh(float v) {
    float a = fabsf(v);
    float e = __expf(-2.f * a);
    float t = (1.f - e) * __builtin_amdgcn_rcpf(1.f + e);
    return copysignf(t, v);
}

// wx[j] = sum_h dense_kernel[h]*gru_kernel[h,j]
// cc[j] = sum_h dense_bias[h]*gru_kernel[h,j] + gru_bias[0][j]
__global__ void prep_wx(const float* __restrict__ dk,
                        const float* __restrict__ db,
                        const float* __restrict__ K,
                        const float* __restrict__ gb,
                        float* __restrict__ wx,
                        float* __restrict__ cc) {
    int j = blockIdx.x * blockDim.x + threadIdx.x;
    if (j >= H3_) return;
    float a = 0.f, c = 0.f;
    for (int h = 0; h < H_; ++h) {
        float kv = K[(size_t)h * H3_ + j];
        a = fmaf(dk[h], kv, a);
        c = fmaf(db[h], kv, c);
    }
    wx[j] = a;
    cc[j] = c + gb[j];
}

// Pack R (H x 3H row-major) into per-(kc,w) fragment-PAIR blocks so one
// dwordx4 per lane fetches two MFMA B fragments:
//   pair block (kc,w,p): 128 ulongs; lane L holds ulongs [2L, 2L+1] =
//   frag f=2p and f=2p+1 lane-L data.
//   frag f: n = g*512 + w*32 + q*16 + (lane&15), k = kc*32 + 8*(lane>>4)+e,
//   with g=f>>1, q=f&1 (p==g, j==q).
__global__ void pack_Rf8(const float* __restrict__ R,
                         unsigned long long* __restrict__ Rp) {
    int idx  = blockIdx.x * 256 + threadIdx.x;    // < 98304
    int lane = idx & 63;
    int fi   = idx >> 6;                          // 0..1535
    int f    = fi % 6;
    int rest = fi / 6;                            // kc*16 + w
    int g    = f >> 1, q = f & 1;
    int w    = rest & 15;
    int n    = g * 512 + w * 32 + q * 16 + (lane & 15);
    int kb   = (rest >> 4) * 32 + 8 * (lane >> 4);
    unsigned long long v = 0;
    #pragma unroll
    for (int e = 0; e < 8; ++e)
        v |= (unsigned long long)f2e4m3(R[(size_t)(kb + e) * H3_ + n]) << (8 * e);
    Rp[(size_t)(rest * 3 + g) * 128 + 2 * lane + q] = v;
}

__global__ __launch_bounds__(1024, 4) void gru_f8(
    const float* __restrict__ x, const float* __restrict__ km,
    const unsigned long long* __restrict__ Rp,
    const float* __restrict__ wx, const float* __restrict__ cc,
    const float* __restrict__ b1,
    float* __restrict__ out0, float* __restrict__ out1)
{
    __shared__ __align__(16) unsigned char st[2][ROWS * 512]; // dbuf fp8 state
    __shared__ float rkm[T_];
    __shared__ int flags[16];                     // steps completed per wave

    const int tid  = threadIdx.x;
    const int lane = tid & 63;
    const int w    = tid >> 6;                    // wave 0..15 -> cols [w*32,+32)
    const int l15  = lane & 15;
    const int lh   = lane >> 4;                   // 0..3
    const int row0 = blockIdx.x * ROWS;
    const bool odd1 = (l15 & 1) != 0;
    const bool odd2 = (l15 & 2) != 0;
    volatile int* vflag = (volatile int*)flags;

    if (tid < T_) rkm[tid] = 1.f / km[tid];
    if (tid < 16) flags[tid] = 0;

    // per-thread gate constants (loop-invariant)
    const int jcq[2] = { w * 32 + l15, w * 32 + 16 + l15 };
    float wxz[2], wxr[2], wxh[2], czc[2], crc[2], cch[2], b1h[2];
    #pragma unroll
    for (int q = 0; q < 2; ++q) {
        int jc = jcq[q];
        wxz[q] = wx[jc];  wxr[q] = wx[512 + jc];  wxh[q] = wx[1024 + jc];
        czc[q] = cc[jc]        + b1[jc];
        crc[q] = cc[512 + jc]  + b1[512 + jc];
        cch[q] = cc[1024 + jc];
        b1h[q] = b1[1024 + jc];
    }

    float hprev[2][2][4];                         // [q][mi][rr] fp32 carry
    #pragma unroll
    for (int q = 0; q < 2; ++q)
        #pragma unroll
        for (int mi = 0; mi < 2; ++mi)
            #pragma unroll
            for (int rr = 0; rr < 4; ++rr) hprev[q][mi][rr] = 0.f;

    // B stream: pair block stride 128 ulongs, kc stride 16*3*128 = 6144
    const unsigned long long* wb = Rp + (size_t)w * 384 + 2 * lane;

    __syncthreads();   // rkm + flags init visible (only barrier in kernel)

    // depth-1 ping-pong: B0 enters each step holding kc=0 (loaded at the
    // previous step's kc=14 phase B wrap, flying through the epilogue).
    lx2 B0[3], B1[3];
    #pragma unroll
    for (int p = 0; p < 3; ++p)
        B0[p] = *(const lx2*)(wb + p * 128);      // kc=0 (for t=1)

    #pragma unroll 1
    for (int t = 0; t < T_; ++t) {
        const char* rd = (const char*)st[t & 1];           // old state
        char*       wr = (char*)st[(t & 1) ^ 1];           // new state

        f32x4 acc[6][2];
        #pragma unroll
        for (int f = 0; f < 6; ++f) {
            acc[f][0] = (f32x4){0.f, 0.f, 0.f, 0.f};
            acc[f][1] = (f32x4){0.f, 0.f, 0.f, 0.f};
        }

        if (t > 0) {
            // seed the pipelined flag cache for body kc=0
            int fp0 = vflag[0];
            int fp1 = vflag[1];
            #pragma unroll 1
            for (int kc = 0; kc < 16; kc += 2) {
                // issue next-phase B prefetch first (flies during checks)
                #pragma unroll
                for (int p = 0; p < 3; ++p)
                    B1[p] = *(const lx2*)(wb + (size_t)(kc + 1) * 6144 + p * 128);
                // flag checks: register fast-path (monotone flags -> stale
                // >= t is safe); volatile spin fallback only on miss.
                if (fp0 < t) { while (vflag[kc]     < t) __builtin_amdgcn_s_sleep(1); }
                if (fp1 < t) { while (vflag[kc + 1] < t) __builtin_amdgcn_s_sleep(1); }
                asm volatile("" ::: "memory");
                // prefetch next body's flags (latency hides under this body)
                if (kc < 14) {
                    fp0 = ((volatile int*)flags)[kc + 2];
                    fp1 = ((volatile int*)flags)[kc + 3];
                }
                // batched A reads for BOTH phases (A(kc+1) hides under
                // MFMA(kc) via the compiler's fine-grained lgkmcnt)
                long A0a = *(const long*)(rd + swz(l15,      kc * 32 + lh * 8));
                long A1a = *(const long*)(rd + swz(l15 + 16, kc * 32 + lh * 8));
                long A0b = *(const long*)(rd + swz(l15,      (kc + 1) * 32 + lh * 8));
                long A1b = *(const long*)(rd + swz(l15 + 16, (kc + 1) * 32 + lh * 8));
                __builtin_amdgcn_s_setprio(1);
                #pragma unroll
                for (int p = 0; p < 3; ++p) {
                    #pragma unroll
                    for (int j = 0; j < 2; ++j) {
                        const int f = 2 * p + j;
                        acc[f][0] = __builtin_amdgcn_mfma_f32_16x16x32_fp8_fp8(
                            A0a, B0[p][j], acc[f][0], 0, 0, 0);
                        acc[f][1] = __builtin_amdgcn_mfma_f32_16x16x32_fp8_fp8(
                            A1a, B0[p][j], acc[f][1], 0, 0, 0);
                    }
                }
                __builtin_amdgcn_s_setprio(0);
                // phase B: prefetch (kc+2)&15 -> B0 (wraps to next step's
                // kc=0 at kc==14 — flies through the epilogue).
                #pragma unroll
                for (int p = 0; p < 3; ++p)
                    B0[p] = *(const lx2*)(wb + (size_t)((kc + 2) & 15) * 6144 + p * 128);
                __builtin_amdgcn_s_setprio(1);
                #pragma unroll
                for (int p = 0; p < 3; ++p) {
                    #pragma unroll
                    for (int j = 0; j < 2; ++j) {
                        const int f = 2 * p + j;
                        acc[f][0] = __builtin_amdgcn_mfma_f32_16x16x32_fp8_fp8(
                            A0b, B1[p][j], acc[f][0], 0, 0, 0);
                        acc[f][1] = __builtin_amdgcn_mfma_f32_16x16x32_fp8_fp8(
                            A1b, B1[p][j], acc[f][1], 0, 0, 0);
                    }
                }
                __builtin_amdgcn_s_setprio(0);
            }
        }

        // gates + state update; reads old plane (rd), writes new plane (wr).
        const float rk = rkm[t];
        #pragma unroll
        for (int mi = 0; mi < 2; ++mi) {
            #pragma unroll
            for (int rr = 0; rr < 4; ++rr) {
                const int brow = mi * 16 + lh * 4 + rr;
                const float cb = ((t == 0)
                    ? x[(size_t)(row0 + brow) * T_]
                    : __builtin_amdgcn_cvt_f32_fp8(
                          (int)((const unsigned char*)rd)[swz(brow, t)], 0)) * rk;
                #pragma unroll
                for (int q = 0; q < 2; ++q) {
                    float z   = fast_sigmoid(fmaf(cb, wxz[q], czc[q])
                                             + acc[q][mi][rr]);
                    float r   = fast_sigmoid(fmaf(cb, wxr[q], crc[q])
                                             + acc[2 + q][mi][rr]);
                    float mhh = acc[4 + q][mi][rr] + b1h[q];
                    float hh  = fast_tanh(fmaf(r, mhh, fmaf(cb, wxh[q], cch[q])));
                    float hn  = fmaf(z, hprev[q][mi][rr] - hh, hh);
                    hprev[q][mi][rr] = hn;
                    // pack 4 consecutive cols (across l15 quads) into one dword:
                    // DPP xor1 swap -> HW cvt_pk (ordered pair) -> xor2 merge.
                    float nb = __shfl_xor(hn, 1);
                    float lo = odd1 ? nb : hn;
                    float hi = odd1 ? hn : nb;
                    unsigned int w16 = (unsigned int)
                        __builtin_amdgcn_cvt_pk_fp8_f32(lo, hi, 0, false);
                    unsigned int v16 = (unsigned int)__shfl_xor((int)w16, 2);
                    unsigned int w32 = (odd2 ? v16 : w16)
                                     | ((odd2 ? w16 : v16) << 16);
                    if ((l15 & 3) == 0)
                        *(unsigned int*)(wr + swz(brow, w * 32 + q * 16 + l15)) = w32;
                }
            }
        }

        // publish: all this wave's LDS reads (phases + colb) and writes done,
        // then raise flag. Consumers spin on it; no block barrier.
        asm volatile("s_waitcnt lgkmcnt(0)" ::: "memory");
        if (lane == 0) vflag[w] = t + 1;
    }

    // final state from fp32 register carry -> both output halves
    #pragma unroll
    for (int q = 0; q < 2; ++q)
        #pragma unroll
        for (int mi = 0; mi < 2; ++mi)
            #pragma unroll
            for (int rr = 0; rr < 4; ++rr) {
                int brow = mi * 16 + lh * 4 + rr;
                size_t o = (size_t)(row0 + brow) * H_ + jcq[q];
                float v = hprev[q][mi][rr];
                out0[o] = v;
                out1[o] = v;
            }
}

extern "C" void kernel_launch(void* const* d_in, const int* in_sizes, int n_in,
                              void* d_out, int out_size, void* d_ws, size_t ws_size,
                              hipStream_t stream) {
    const float* x  = (const float*)d_in[0];
    const float* km = (const float*)d_in[1];
    const float* dk = (const float*)d_in[2];
    const float* db = (const float*)d_in[3];
    const float* K  = (const float*)d_in[4];
    const float* R  = (const float*)d_in[5];
    const float* gb = (const float*)d_in[6];

    float* out  = (float*)d_out;
    float* out1 = out + BH;

    float* wx = (float*)d_ws;                     // 1536 f
    float* cc = wx + H3_;                         // 1536 f
    unsigned long long* Rp = (unsigned long long*)(cc + H3_);   // 768 KB

    prep_wx<<<dim3((H3_ + 255) / 256), 256, 0, stream>>>(dk, db, K, gb, wx, cc);
    pack_Rf8<<<dim3(384), 256, 0, stream>>>(R, Rp);

    gru_f8<<<dim3(256), dim3(1024), 0, stream>>>(
        x, km, Rp, wx, cc, gb + H3_, out, out1);
}

// Round 13
// 3515.970 us; speedup vs baseline: 1.3041x; 1.0145x over previous
//
#include <hip/hip_runtime.h>
#include <hip/hip_bf16.h>
#include <hip/hip_fp8.h>
#include <math.h>

// Encoder GRU, B=8192 T=256 H=512 — sync-free state-resident, v16.
// v8 structure (per-wave flags, dbuf state, half-phase triple B loads,
// setprio, quad-shuffle state pack) with the matmul moved to INT8 MFMA:
//   mfma_i32_16x16x64_i8 — 2x the fp8 rate (3944 vs 2047 TOPS, m16),
//   K=64/instr -> 96 MFMA/wave/step (was 192), MFMA floor 6.2 -> 3.1 us.
// Quantization (accuracy >= fp8 path that measured absmax 0.0):
//   state: |h|<=1 by induction (convex combo of tanh outputs) -> symmetric
//     i8, scale 127 (grid 0.008 vs fp8's ~6% relative step).
//   R: global scale sR=max|R| (atomicMax reduction), Rq=rint(R/sR*127).
//   acc is EXACT int32; dequant = one SGPR const sR/127^2 per value.
// Register budget: +4 vs v8 (A = 16B/row-tile), phase-local live range —
// v15's spill was +8 regs live ACROSS clusters; this stays within-phase.
// d_in: x(B,T), kmforenc(T), dense_kernel(1,H), dense_bias(H),
//       gru_kernel(H,3H), gru_recurrent(H,3H), gru_bias(2,3H)

constexpr int B_  = 8192;
constexpr int T_  = 256;
constexpr int H_  = 512;
constexpr int H3_ = 1536;
constexpr size_t BH = (size_t)B_ * H_;
constexpr int ROWS = 32;

typedef float f32x4 __attribute__((ext_vector_type(4)));
typedef int   i32x4 __attribute__((ext_vector_type(4)));

// swizzled byte offset into one i8 state plane [32 rows][512 cols]
__device__ __forceinline__ int swz(int row, int col) {
    return (row * 512 + col) ^ ((row & 15) << 3);
}
__device__ __forceinline__ float fast_sigmoid(float v) {
    return __builtin_amdgcn_rcpf(1.f + __expf(-v));
}
__device__ __forceinline__ float fast_tanh(float v) {
    float a = fabsf(v);
    float e = __expf(-2.f * a);
    float t = (1.f - e) * __builtin_amdgcn_rcpf(1.f + e);
    return copysignf(t, v);
}

__global__ void zero_u32(unsigned* p) { *p = 0u; }

// global max|R| via wave-reduce + atomicMax on float bits (non-negative
// floats compare correctly as uints)
__global__ void rmax_R(const float* __restrict__ R, unsigned* __restrict__ smax) {
    size_t tid = (size_t)blockIdx.x * 256 + threadIdx.x;
    float m = 0.f;
    for (size_t i = tid; i < (size_t)H_ * H3_; i += 65536)
        m = fmaxf(m, fabsf(R[i]));
    #pragma unroll
    for (int off = 32; off; off >>= 1)
        m = fmaxf(m, __shfl_down(m, off));
    if ((threadIdx.x & 63) == 0)
        atomicMax(smax, __float_as_uint(m));
}

// wx[j] = sum_h dense_kernel[h]*gru_kernel[h,j]
// cc[j] = sum_h dense_bias[h]*gru_kernel[h,j] + gru_bias[0][j]
__global__ void prep_wx(const float* __restrict__ dk,
                        const float* __restrict__ db,
                        const float* __restrict__ K,
                        const float* __restrict__ gb,
                        float* __restrict__ wx,
                        float* __restrict__ cc) {
    int j = blockIdx.x * blockDim.x + threadIdx.x;
    if (j >= H3_) return;
    float a = 0.f, c = 0.f;
    for (int h = 0; h < H_; ++h) {
        float kv = K[(size_t)h * H3_ + j];
        a = fmaf(dk[h], kv, a);
        c = fmaf(db[h], kv, c);
    }
    wx[j] = a;
    cc[j] = c + gb[j];
}

// Pack Rq (i8) into per-(ph,w,f) 1 KB fragment blocks for mfma 16x16x64:
//   frag f (g=f>>1, q=f&1): n = g*512 + w*32 + q*16 + (lane&15),
//   k = ph*64 + 16*(lane>>4) + e (e=0..15); lane holds bytes [16L,16L+16).
// Same (lane-group, byte)->k map as the A fragment -> correct under any HW
// k-permutation (k-symmetric packing, as verified for the fp8 path).
__global__ void pack_Ri8(const float* __restrict__ R,
                         const unsigned* __restrict__ smax,
                         unsigned long long* __restrict__ Rp) {
    int idx  = blockIdx.x * 256 + threadIdx.x;    // < 98304
    int h8   = idx & 1;                           // which 8B of the lane's 16B
    int lane = (idx >> 1) & 63;
    int bi   = idx >> 7;                          // (ph*16 + w)*6 + f, 0..767
    int f    = bi % 6;
    int rest = bi / 6;
    int w    = rest & 15;
    int ph   = rest >> 4;
    int g    = f >> 1, q = f & 1;
    int n    = g * 512 + w * 32 + q * 16 + (lane & 15);
    int k0   = ph * 64 + 16 * (lane >> 4) + h8 * 8;
    float sR = __uint_as_float(*smax);
    float qs = (sR > 0.f) ? 127.f / sR : 0.f;
    unsigned long long v = 0;
    #pragma unroll
    for (int e = 0; e < 8; ++e) {
        int qb = (int)__builtin_rintf(R[(size_t)(k0 + e) * H3_ + n] * qs);
        qb = qb > 127 ? 127 : (qb < -127 ? -127 : qb);
        v |= (unsigned long long)((unsigned)qb & 0xffu) << (8 * e);
    }
    Rp[(size_t)bi * 128 + lane * 2 + h8] = v;
}

__global__ __launch_bounds__(1024, 4) void gru_i8(
    const float* __restrict__ x, const float* __restrict__ km,
    const unsigned long long* __restrict__ Rp,
    const unsigned* __restrict__ smax,
    const float* __restrict__ wx, const float* __restrict__ cc,
    const float* __restrict__ b1,
    float* __restrict__ out0, float* __restrict__ out1)
{
    __shared__ __align__(16) unsigned char st[2][ROWS * 512]; // dbuf i8 state
    __shared__ float rkm[T_];
    __shared__ int flags[16];                     // steps completed per wave

    const int tid  = threadIdx.x;
    const int lane = tid & 63;
    const int w    = tid >> 6;                    // wave 0..15 -> cols [w*32,+32)
    const int l15  = lane & 15;
    const int lh   = lane >> 4;                   // 0..3
    const int row0 = blockIdx.x * ROWS;
    const bool odd1 = (l15 & 1) != 0;
    const bool odd2 = (l15 & 2) != 0;
    volatile int* vflag = (volatile int*)flags;

    if (tid < T_) rkm[tid] = 1.f / km[tid];
    if (tid < 16) flags[tid] = 0;

    // dequant constant: acc * sR/127^2 = true sum(h*R)
    const float accScale = __uint_as_float(*smax) * (1.f / 16129.f);

    // per-thread gate constants (loop-invariant)
    const int jcq[2] = { w * 32 + l15, w * 32 + 16 + l15 };
    float wxz[2], wxr[2], wxh[2], czc[2], crc[2], cch[2], b1h[2];
    #pragma unroll
    for (int q = 0; q < 2; ++q) {
        int jc = jcq[q];
        wxz[q] = wx[jc];  wxr[q] = wx[512 + jc];  wxh[q] = wx[1024 + jc];
        czc[q] = cc[jc]        + b1[jc];
        crc[q] = cc[512 + jc]  + b1[512 + jc];
        cch[q] = cc[1024 + jc];
        b1h[q] = b1[1024 + jc];
    }

    float hprev[2][2][4];                         // [q][mi][rr] fp32 carry
    #pragma unroll
    for (int q = 0; q < 2; ++q)
        #pragma unroll
        for (int mi = 0; mi < 2; ++mi)
            #pragma unroll
            for (int rr = 0; rr < 4; ++rr) hprev[q][mi][rr] = 0.f;

    // B stream: frag block 1 KB, wave base w*6KB, phase stride 96 KB
    const char* wbc = (const char*)Rp + w * 6144 + 16 * lane;

    __syncthreads();   // rkm + flags init visible (only barrier in kernel)

    // two rolling triples: T0 = frags 0-2, T1 = frags 3-5 of the current
    // phase; refilled mid-phase for phase+1 (ph=7 wraps to next step's 0,
    // flying through the epilogue). 24 VGPRs — same budget as v8's B0/B1.
    i32x4 T0[3], T1[3];
    #pragma unroll
    for (int p = 0; p < 3; ++p) {
        T0[p] = *(const i32x4*)(wbc + p * 1024);
        T1[p] = *(const i32x4*)(wbc + 3072 + p * 1024);
    }

    #pragma unroll 1
    for (int t = 0; t < T_; ++t) {
        const char* rd = (const char*)st[t & 1];           // old state
        char*       wr = (char*)st[(t & 1) ^ 1];           // new state

        i32x4 acc[6][2];
        #pragma unroll
        for (int f = 0; f < 6; ++f) {
            acc[f][0] = (i32x4){0, 0, 0, 0};
            acc[f][1] = (i32x4){0, 0, 0, 0};
        }

        if (t > 0) {
            #pragma unroll 1
            for (int ph = 0; ph < 8; ++ph) {
                // producers of state cols [ph*64, +64)
                while (vflag[2 * ph] < t || vflag[2 * ph + 1] < t)
                    __builtin_amdgcn_s_sleep(1);
                asm volatile("" ::: "memory");
                // A fragments: row tiles, k = ph*64 + 16*lh + e (e=0..15)
                const int c0 = ph * 64 + 16 * lh;
                long a0lo = *(const long*)(rd + swz(l15,      c0));
                long a0hi = *(const long*)(rd + swz(l15,      c0 + 8));
                long a1lo = *(const long*)(rd + swz(l15 + 16, c0));
                long a1hi = *(const long*)(rd + swz(l15 + 16, c0 + 8));
                i32x4 A0, A1;
                A0[0] = (int)a0lo; A0[1] = (int)(a0lo >> 32);
                A0[2] = (int)a0hi; A0[3] = (int)(a0hi >> 32);
                A1[0] = (int)a1lo; A1[1] = (int)(a1lo >> 32);
                A1[2] = (int)a1hi; A1[3] = (int)(a1hi >> 32);
                const char* nxt = wbc + (size_t)((ph + 1) & 7) * 98304;

                __builtin_amdgcn_s_setprio(1);
                #pragma unroll
                for (int p = 0; p < 3; ++p) {
                    acc[p][0] = __builtin_amdgcn_mfma_i32_16x16x64_i8(
                        A0, T0[p], acc[p][0], 0, 0, 0);
                    acc[p][1] = __builtin_amdgcn_mfma_i32_16x16x64_i8(
                        A1, T0[p], acc[p][1], 0, 0, 0);
                }
                __builtin_amdgcn_s_setprio(0);
                #pragma unroll
                for (int p = 0; p < 3; ++p)
                    T0[p] = *(const i32x4*)(nxt + p * 1024);
                __builtin_amdgcn_s_setprio(1);
                #pragma unroll
                for (int p = 0; p < 3; ++p) {
                    acc[3 + p][0] = __builtin_amdgcn_mfma_i32_16x16x64_i8(
                        A0, T1[p], acc[3 + p][0], 0, 0, 0);
                    acc[3 + p][1] = __builtin_amdgcn_mfma_i32_16x16x64_i8(
                        A1, T1[p], acc[3 + p][1], 0, 0, 0);
                }
                __builtin_amdgcn_s_setprio(0);
                #pragma unroll
                for (int p = 0; p < 3; ++p)
                    T1[p] = *(const i32x4*)(nxt + 3072 + p * 1024);
            }
        }

        // gates + state update; reads old plane (rd), writes new plane (wr).
        const float rk    = rkm[t];
        const float rk127 = rk * (1.f / 127.f);
        #pragma unroll
        for (int mi = 0; mi < 2; ++mi) {
            #pragma unroll
            for (int rr = 0; rr < 4; ++rr) {
                const int brow = mi * 16 + lh * 4 + rr;
                const float cb = (t == 0)
                    ? x[(size_t)(row0 + brow) * T_] * rk
                    : (float)*(const signed char*)(rd + swz(brow, t)) * rk127;
                #pragma unroll
                for (int q = 0; q < 2; ++q) {
                    float az  = (float)acc[q][mi][rr]     * accScale;
                    float ar  = (float)acc[2 + q][mi][rr] * accScale;
                    float ah  = (float)acc[4 + q][mi][rr] * accScale;
                    float z   = fast_sigmoid(fmaf(cb, wxz[q], czc[q]) + az);
                    float r   = fast_sigmoid(fmaf(cb, wxr[q], crc[q]) + ar);
                    float mhh = ah + b1h[q];
                    float hh  = fast_tanh(fmaf(r, mhh, fmaf(cb, wxh[q], cch[q])));
                    float hn  = fmaf(z, hprev[q][mi][rr] - hh, hh);
                    hprev[q][mi][rr] = hn;
                    // quantize to i8 and pack 4 consecutive cols (across
                    // l15 quads) into one dword — v3's byte-merge pattern.
                    unsigned bb = (unsigned)((int)__builtin_rintf(hn * 127.f)) & 0xffu;
                    unsigned pp = (unsigned)__shfl_xor((int)bb, 1);
                    unsigned w16 = odd1 ? (pp | (bb << 8)) : (bb | (pp << 8));
                    unsigned p2 = (unsigned)__shfl_xor((int)w16, 2);
                    unsigned w32 = odd2 ? (p2 | (w16 << 16)) : (w16 | (p2 << 16));
                    if ((l15 & 3) == 0)
                        *(unsigned int*)(wr + swz(brow, w * 32 + q * 16 + l15)) = w32;
                }
            }
        }

        // publish: all this wave's LDS reads (phases + colb) and writes done,
        // then raise flag. Consumers spin on it; no block barrier.
        asm volatile("s_waitcnt lgkmcnt(0)" ::: "memory");
        if (lane == 0) vflag[w] = t + 1;
    }

    // final state from fp32 register carry -> both output halves
    #pragma unroll
    for (int q = 0; q < 2; ++q)
        #pragma unroll
        for (int mi = 0; mi < 2; ++mi)
            #pragma unroll
            for (int rr = 0; rr < 4; ++rr) {
                int brow = mi * 16 + lh * 4 + rr;
                size_t o = (size_t)(row0 + brow) * H_ + jcq[q];
                float v = hprev[q][mi][rr];
                out0[o] = v;
                out1[o] = v;
            }
}

extern "C" void kernel_launch(void* const* d_in, const int* in_sizes, int n_in,
                              void* d_out, int out_size, void* d_ws, size_t ws_size,
                              hipStream_t stream) {
    const float* x  = (const float*)d_in[0];
    const float* km = (const float*)d_in[1];
    const float* dk = (const float*)d_in[2];
    const float* db = (const float*)d_in[3];
    const float* K  = (const float*)d_in[4];
    const float* R  = (const float*)d_in[5];
    const float* gb = (const float*)d_in[6];

    float* out  = (float*)d_out;
    float* out1 = out + BH;

    float* wx = (float*)d_ws;                     // 1536 f
    float* cc = wx + H3_;                         // 1536 f
    unsigned* smax = (unsigned*)(cc + H3_);       // 1 u32 (+pad)
    unsigned long long* Rp =
        (unsigned long long*)((char*)d_ws + 12304);            // 768 KB

    zero_u32<<<dim3(1), dim3(1), 0, stream>>>(smax);
    rmax_R<<<dim3(256), dim3(256), 0, stream>>>(R, smax);
    prep_wx<<<dim3((H3_ + 255) / 256), 256, 0, stream>>>(dk, db, K, gb, wx, cc);
    pack_Ri8<<<dim3(384), 256, 0, stream>>>(R, smax, Rp);

    gru_i8<<<dim3(256), dim3(1024), 0, stream>>>(
        x, km, Rp, smax, wx, cc, gb + H3_, out, out1);
}